// Round 17
// baseline (39.859 us; speedup 1.0000x reference)
//
#include <hip/hip_runtime.h>
#include <hip/hip_bf16.h>
#include <math.h>

#define NPC   2048          // points per cloud
#define NC    8             // clouds
#define NTOT  (NPC * NC)    // 16384
#define KMAX  32
#define R2    0.04f         // f32(0.04) — boundary-exact vs numpy's f64 compare

typedef short bf16x8  __attribute__((ext_vector_type(8)));
typedef float f32x16  __attribute__((ext_vector_type(16)));

// f32 -> bf16 round-to-nearest-even (finite values only)
__device__ __forceinline__ unsigned int f2bf(float f) {
    unsigned int u = __float_as_uint(f);
    return (u + 0x7FFFu + ((u >> 16) & 1u)) >> 16;
}

// packed f32x2 -> bf16x2 (RNE), src0 in LOW half (validated round 5)
__device__ __forceinline__ unsigned int pkbf(float a, float b) {
    unsigned int r;
    asm("v_cvt_pk_bf16_f32 %0, %1, %2" : "=v"(r) : "v"(a), "v"(b));
    return r;
}

// count of set bits in m at positions < lane (wave64) — 2 VALU instrs
__device__ __forceinline__ int mbcnt64(unsigned long long m) {
    return (int)__builtin_amdgcn_mbcnt_hi((unsigned int)(m >> 32),
            __builtin_amdgcn_mbcnt_lo((unsigned int)m, 0u));
}

// ---- k-permuted epilogue (validated round 8): relu+pack 8 consecutive acc regs -> operand frag ----
// Weight k-rows pre-permuted by P(kk,hi,j) = (j&3)+4*hi+8*(2*(kk&1)+(j>>2))+32*(kk>>1).
__device__ __forceinline__ bf16x8 mk_frag(const f32x16& a, int off) {  // off: 0 or 8 (compile-time)
    int4 w;
    w.x = (int)pkbf(fmaxf(a[off+0],0.f), fmaxf(a[off+1],0.f));
    w.y = (int)pkbf(fmaxf(a[off+2],0.f), fmaxf(a[off+3],0.f));
    w.z = (int)pkbf(fmaxf(a[off+4],0.f), fmaxf(a[off+5],0.f));
    w.w = (int)pkbf(fmaxf(a[off+6],0.f), fmaxf(a[off+7],0.f));
    return __builtin_bit_cast(bf16x8, w);
}

// ============ kernel 1 (tiny): weight frags (k-permuted, validated r8/r9) + tail copies ============
__global__ __launch_bounds__(512) void prep_small(
    const float* __restrict__ pos, const int* __restrict__ batch,
    const float* __restrict__ W1, const float* __restrict__ b1,
    const float* __restrict__ W2, const float* __restrict__ b2,
    const float* __restrict__ W3,
    unsigned short* __restrict__ wf, float* __restrict__ out)
{
    int b = blockIdx.x, tid = threadIdx.x;
    if (b < 28) {
        int g = b * 512 + tid;                // 0..14335
        if (g < 1024) {
            int j = g & 7, lane = (g >> 3) & 63, t = g >> 9;
            int k = (lane >> 5)*8 + j, ch = t*32 + (lane & 31);
            float v = (k < 6) ? W1[k*64 + ch] : (k == 6 ? b1[ch] : 0.f);
            wf[g] = (unsigned short)f2bf(v);
        } else if (g < 6144) {
            int g2 = g - 1024;
            int j = g2 & 7, lane = (g2 >> 3) & 63, f = g2 >> 9;
            int t = f / 5, kk = f % 5;
            int hi = lane >> 5, row = t*32 + (lane & 31);
            float v;
            if (kk < 4) {
                int k = (j & 3) + 4*hi + 8*(2*(kk & 1) + (j >> 2)) + 32*(kk >> 1);
                v = W2[k*64 + row];
            } else {
                v = (hi == 0 && j == 0) ? b2[row] : 0.f;   // bias row, matches `onef` B-frag
            }
            wf[g] = (unsigned short)f2bf(v);
        } else {
            int g3 = g - 6144;
            int j = g3 & 7, lane = (g3 >> 3) & 63, f = g3 >> 9;
            int n = f >> 2, kk = f & 3;
            int hi = lane >> 5, col = n*32 + (lane & 31);
            int k = (j & 3) + 4*hi + 8*(2*(kk & 1) + (j >> 2)) + 32*(kk >> 1);
            wf[g] = (unsigned short)f2bf(W3[k*128 + col]);
        }
    } else {
        int i = (b - 28) * 512 + tid;
        if (i < NTOT*3) out[NTOT*128 + i] = pos[i];
        else            out[NTOT*131 + (i - NTOT*3)] = (float)batch[i - NTOT*3];
    }
}

// ---- search body (r13-validated exact arithmetic), expanded statically per query ----
#define SEARCH_BODY(QX, QY, QZ, CNT, NOFF)                                              \
    {                                                                                   \
        for (int j0 = 0; j0 < NPC && CNT < KMAX; j0 += 256) {                           \
            unsigned long long ms_[4];                                                  \
            bool vs_[4];                                                                \
            _Pragma("unroll")                                                           \
            for (int s = 0; s < 4; ++s) {                                               \
                int j = j0 + s*64 + lane;                                               \
                float2 pxy = sPxy[j];                                                   \
                float  pz  = sPz[j];                                                    \
                float dx = __fsub_rn(pxy.x, QX);                                        \
                float dy = __fsub_rn(pxy.y, QY);                                        \
                float dz = __fsub_rn(pz,    QZ);                                        \
                float d2 = __fadd_rn(__fadd_rn(__fmul_rn(dx,dx), __fmul_rn(dy,dy)),     \
                                     __fmul_rn(dz,dz));                                 \
                vs_[s] = d2 <= R2;                                                      \
                ms_[s] = __ballot(vs_[s]);                                              \
            }                                                                           \
            _Pragma("unroll")                                                           \
            for (int s = 0; s < 4; ++s) {                                               \
                int slot = CNT + mbcnt64(ms_[s]);                                       \
                if (vs_[s] && slot < KMAX) snbr[(NOFF) + slot] = j0 + s*64 + lane;      \
                CNT += (int)__popcll(ms_[s]);                                           \
            }                                                                           \
        }                                                                               \
        if (CNT > KMAX) CNT = KMAX;                                                     \
    }

// ---- MLP body (r13-validated), expanded statically per query ----
#define MLP_BODY(Q, QL, CNT, NOFF, QX, QY, QZ)                                          \
    {                                                                                   \
        int jl = (e < CNT) ? snbr[(NOFF) + e] : (QL);                                   \
        float2 pjxy = sPxy[jl];                                                         \
        float  pjz  = sPz[jl];                                                          \
        int gj = base + jl;                                                             \
        float xj0 = x[3*gj], xj1 = x[3*gj+1], xj2 = x[3*gj+2];                          \
        float r0 = pjxy.x - (QX), r1 = pjxy.y - (QY), r2 = pjz - (QZ);                  \
        int4 mw;                                                                        \
        mw.x = hi ? 0 : (int)pkbf(xj0, xj1);                                            \
        mw.y = hi ? 0 : (int)pkbf(xj2, r0);                                             \
        mw.z = hi ? 0 : (int)pkbf(r1, r2);                                              \
        mw.w = hi ? 0 : (int)one_w;                                                     \
        bf16x8 msgf = __builtin_bit_cast(bf16x8, mw);                                   \
        __builtin_amdgcn_s_setprio(1);                                                  \
        f32x16 acc0 = {}, acc1 = {};                                                    \
        acc0 = __builtin_amdgcn_mfma_f32_32x32x16_bf16(wA1_0, msgf, acc0, 0, 0, 0);     \
        acc1 = __builtin_amdgcn_mfma_f32_32x32x16_bf16(wA1_1, msgf, acc1, 0, 0, 0);     \
        __builtin_amdgcn_s_setprio(0);                                                  \
        bf16x8 h1f[4];                                                                  \
        h1f[0] = mk_frag(acc0, 0);                                                      \
        h1f[1] = mk_frag(acc0, 8);                                                      \
        h1f[2] = mk_frag(acc1, 0);                                                      \
        h1f[3] = mk_frag(acc1, 8);                                                      \
        __builtin_amdgcn_s_setprio(1);                                                  \
        f32x16 c20 = {}, c21 = {};                                                      \
        _Pragma("unroll")                                                               \
        for (int kk = 0; kk < 4; ++kk) {                                                \
            c20 = __builtin_amdgcn_mfma_f32_32x32x16_bf16(                              \
                    *(const bf16x8*)&sW[(0*5 + kk)*64 + lane], h1f[kk], c20, 0, 0, 0);  \
            c21 = __builtin_amdgcn_mfma_f32_32x32x16_bf16(                              \
                    *(const bf16x8*)&sW[(1*5 + kk)*64 + lane], h1f[kk], c21, 0, 0, 0);  \
        }                                                                               \
        c20 = __builtin_amdgcn_mfma_f32_32x32x16_bf16(                                  \
                *(const bf16x8*)&sW[(0*5 + 4)*64 + lane], onef, c20, 0, 0, 0);          \
        c21 = __builtin_amdgcn_mfma_f32_32x32x16_bf16(                                  \
                *(const bf16x8*)&sW[(1*5 + 4)*64 + lane], onef, c21, 0, 0, 0);          \
        __builtin_amdgcn_s_setprio(0);                                                  \
        bf16x8 h2f[4];                                                                  \
        h2f[0] = mk_frag(c20, 0);                                                       \
        h2f[1] = mk_frag(c20, 8);                                                       \
        h2f[2] = mk_frag(c21, 0);                                                       \
        h2f[3] = mk_frag(c21, 8);                                                       \
        const bool full = (CNT == 32);                                                  \
        _Pragma("unroll")                                                               \
        for (int n = 0; n < 4; ++n) {                                                   \
            __builtin_amdgcn_s_setprio(1);                                              \
            f32x16 c = {};                                                              \
            _Pragma("unroll")                                                           \
            for (int kk = 0; kk < 4; ++kk)                                              \
                c = __builtin_amdgcn_mfma_f32_32x32x16_bf16(                            \
                        h2f[kk], *(const bf16x8*)&sW[640 + (n*4 + kk)*64 + lane],       \
                        c, 0, 0, 0);                                                    \
            __builtin_amdgcn_s_setprio(0);                                              \
            float m;                                                                    \
            if (full) {                                                                 \
                float t0 = fmaxf(fmaxf(c[0],  c[1]),  c[2]);                            \
                float t1 = fmaxf(fmaxf(c[3],  c[4]),  c[5]);                            \
                float t2 = fmaxf(fmaxf(c[6],  c[7]),  c[8]);                            \
                float t3 = fmaxf(fmaxf(c[9],  c[10]), c[11]);                           \
                float t4 = fmaxf(fmaxf(c[12], c[13]), c[14]);                           \
                m = fmaxf(fmaxf(t0, t1), c[15]);                                        \
                m = fmaxf(fmaxf(m, t2), t3);                                            \
                m = fmaxf(m, t4);                                                       \
            } else {                                                                    \
                m = -INFINITY;                                                          \
                _Pragma("unroll")                                                       \
                for (int reg = 0; reg < 16; ++reg) {                                    \
                    int r = (reg & 3) + 8*(reg >> 2) + 4*hi;                            \
                    m = fmaxf(m, (r < CNT) ? c[reg] : -INFINITY);                       \
                }                                                                       \
            }                                                                           \
            m = fmaxf(m, __shfl_xor(m, 32));                                            \
            m += b3v[n];                                                                \
            if (hi == 0) out[(Q)*128 + n*32 + e] = m;                                   \
        }                                                                               \
    }

// ============ kernel 2: FUSED search + MLP, 16 waves x Q=2-sequential = 32 queries/block ============
// Grid 512 -> ALL blocks resident (2/CU, 32 waves/CU): zero dispatch queue, staging paid once
// per 32 queries, per-wave time = sum of 2 iid queries (variance averaged).
// LDS: sPxy 16K + sPz 8K + sW 26K + snbr 4K = 54.6 KB -> 2 blocks/CU.
__global__ __launch_bounds__(1024, 8) void fused_kernel(
    const float* __restrict__ x, const float* __restrict__ pos,
    const unsigned short* __restrict__ wf, const float* __restrict__ b3,
    float* __restrict__ out)
{
    __shared__ float2 sPxy[NPC];     // 16384 B
    __shared__ float  sPz[NPC];      //  8192 B
    __shared__ int4   sW[1664];      // 26624 B: wg2a(640) | wg3b(1024)
    __shared__ int    snbr[16*64];   //  4096 B: per wave: [0..31] q0, [32..63] q1

    const int tid  = threadIdx.x;
    const int lane = tid & 63, wave = tid >> 6;
    const int e = lane & 31, hi = lane >> 5;
    const int q0    = __builtin_amdgcn_readfirstlane(blockIdx.x * 32 + wave * 2);
    const int base  = (q0 >> 11) << 11;           // cloud start row (q0,q1 same cloud)
    const int q0l   = q0 - base;
    const int woff  = wave << 6;

    // ---- Phase A: parallel staging — half block: pos SoA; other half: weight frags ----
    if (tid < 512) {
        const float4* src = (const float4*)(pos + 3*base);   // 1536 float4 = 2048 points
        float4 f0 = src[3*tid], f1 = src[3*tid+1], f2 = src[3*tid+2];
        sPxy[4*tid+0] = make_float2(f0.x, f0.y); sPz[4*tid+0] = f0.z;
        sPxy[4*tid+1] = make_float2(f0.w, f1.x); sPz[4*tid+1] = f1.y;
        sPxy[4*tid+2] = make_float2(f1.z, f1.w); sPz[4*tid+2] = f2.x;
        sPxy[4*tid+3] = make_float2(f2.y, f2.z); sPz[4*tid+3] = f2.w;
    } else {
        const int4* wsrc = (const int4*)(wf + 1024);
        int t = tid - 512;
        #pragma unroll
        for (int it = 0; it < 4; ++it) {
            int idx = it*512 + t;
            if (idx < 1664) sW[idx] = wsrc[idx];
        }
    }
    bf16x8 wA1_0 = *(const bf16x8*)(wf + (0*64 + lane)*8);
    bf16x8 wA1_1 = *(const bf16x8*)(wf + (1*64 + lane)*8);
    float b3v[4];
    #pragma unroll
    for (int n = 0; n < 4; ++n) b3v[n] = b3[n*32 + e];
    __syncthreads();   // the ONLY block-wide barrier

    const unsigned int one_w = pkbf(1.0f, 0.0f);
    int4 ow = {0,0,0,0};
    if (!hi) ow.x = (int)one_w;
    const bf16x8 onef = __builtin_bit_cast(bf16x8, ow);   // GEMM2 bias-row B-frag

    // query centers
    const float2 q0xy = sPxy[q0l];
    const float q0x = q0xy.x, q0y = q0xy.y, q0z = sPz[q0l];
    const float2 q1xy = sPxy[q0l + 1];
    const float q1x = q1xy.x, q1y = q1xy.y, q1z = sPz[q0l + 1];

    // ---- query 0: search then MLP ----
    int cnt0 = 0;
    SEARCH_BODY(q0x, q0y, q0z, cnt0, woff)
    MLP_BODY(q0, q0l, cnt0, woff, q0x, q0y, q0z)

    // ---- query 1: search then MLP ----
    int cnt1 = 0;
    SEARCH_BODY(q1x, q1y, q1z, cnt1, woff + 32)
    MLP_BODY(q0 + 1, q0l + 1, cnt1, woff + 32, q1x, q1y, q1z)
}

extern "C" void kernel_launch(void* const* d_in, const int* in_sizes, int n_in,
                              void* d_out, int out_size, void* d_ws, size_t ws_size,
                              hipStream_t stream) {
    const float* x     = (const float*)d_in[0];
    const float* pos   = (const float*)d_in[1];
    const int*   batch = (const int*)d_in[2];
    const float* W1    = (const float*)d_in[3];
    const float* b1    = (const float*)d_in[4];
    const float* W2    = (const float*)d_in[5];
    const float* b2    = (const float*)d_in[6];
    const float* W3    = (const float*)d_in[7];
    const float* b3    = (const float*)d_in[8];
    float* out = (float*)d_out;

    unsigned short* wfrag = (unsigned short*)d_ws;   // 14336 bf16 (28 KB)

    prep_small<<<156, 512, 0, stream>>>(pos, batch, W1, b1, W2, b2, W3, wfrag, out);
    fused_kernel<<<NTOT / 32, 1024, 0, stream>>>(x, pos, wfrag, b3, out);
}

// Round 18
// 34.892 us; speedup vs baseline: 1.1424x; 1.1424x over previous
//
#include <hip/hip_runtime.h>
#include <hip/hip_bf16.h>
#include <math.h>

#define NPC   2048          // points per cloud
#define NC    8             // clouds
#define NTOT  (NPC * NC)    // 16384
#define KMAX  32
#define R2    0.04f         // f32(0.04) — boundary-exact vs numpy's f64 compare

typedef short bf16x8  __attribute__((ext_vector_type(8)));
typedef float f32x16  __attribute__((ext_vector_type(16)));

// f32 -> bf16 round-to-nearest-even (finite values only)
__device__ __forceinline__ unsigned int f2bf(float f) {
    unsigned int u = __float_as_uint(f);
    return (u + 0x7FFFu + ((u >> 16) & 1u)) >> 16;
}

// packed f32x2 -> bf16x2 (RNE), src0 in LOW half (validated round 5)
__device__ __forceinline__ unsigned int pkbf(float a, float b) {
    unsigned int r;
    asm("v_cvt_pk_bf16_f32 %0, %1, %2" : "=v"(r) : "v"(a), "v"(b));
    return r;
}

// count of set bits in m at positions < lane (wave64) — 2 VALU instrs
__device__ __forceinline__ int mbcnt64(unsigned long long m) {
    return (int)__builtin_amdgcn_mbcnt_hi((unsigned int)(m >> 32),
            __builtin_amdgcn_mbcnt_lo((unsigned int)m, 0u));
}

// ---- k-permuted epilogue (validated round 8): relu+pack 8 consecutive acc regs -> operand frag ----
// Prep permutes the NEXT layer's weight k-rows by
// P(kk,hi,j) = (j&3) + 4*hi + 8*(2*(kk&1)+(j>>2)) + 32*(kk>>1)  == accumulator's natural row order.
__device__ __forceinline__ bf16x8 mk_frag(const f32x16& a, int off) {  // off: 0 or 8 (compile-time)
    int4 w;
    w.x = (int)pkbf(fmaxf(a[off+0],0.f), fmaxf(a[off+1],0.f));
    w.y = (int)pkbf(fmaxf(a[off+2],0.f), fmaxf(a[off+3],0.f));
    w.z = (int)pkbf(fmaxf(a[off+4],0.f), fmaxf(a[off+5],0.f));
    w.w = (int)pkbf(fmaxf(a[off+6],0.f), fmaxf(a[off+7],0.f));
    return __builtin_bit_cast(bf16x8, w);
}

// ============ kernel 1 (tiny): weight frags (k-permuted, validated r8/r9) + tail copies ============
__global__ __launch_bounds__(512) void prep_small(
    const float* __restrict__ pos, const int* __restrict__ batch,
    const float* __restrict__ W1, const float* __restrict__ b1,
    const float* __restrict__ W2, const float* __restrict__ b2,
    const float* __restrict__ W3,
    unsigned short* __restrict__ wf, float* __restrict__ out)
{
    int b = blockIdx.x, tid = threadIdx.x;
    if (b < 28) {
        int g = b * 512 + tid;                // 0..14335
        if (g < 1024) {
            // layer1 A = W1^T padded K=16, bias at k=6 (natural k order)
            int j = g & 7, lane = (g >> 3) & 63, t = g >> 9;
            int k = (lane >> 5)*8 + j, ch = t*32 + (lane & 31);
            float v = (k < 6) ? W1[k*64 + ch] : (k == 6 ? b1[ch] : 0.f);
            wf[g] = (unsigned short)f2bf(v);
        } else if (g < 6144) {
            // GEMM2 A = W2^T (K=80, bias row at logical k=64); k-rows permuted by P
            int g2 = g - 1024;
            int j = g2 & 7, lane = (g2 >> 3) & 63, f = g2 >> 9;
            int t = f / 5, kk = f % 5;
            int hi = lane >> 5, row = t*32 + (lane & 31);
            float v;
            if (kk < 4) {
                int k = (j & 3) + 4*hi + 8*(2*(kk & 1) + (j >> 2)) + 32*(kk >> 1);
                v = W2[k*64 + row];
            } else {
                v = (hi == 0 && j == 0) ? b2[row] : 0.f;   // bias row, matches `onef` B-frag
            }
            wf[g] = (unsigned short)f2bf(v);
        } else {
            // GEMM3 B = W3 (K=64); k-rows permuted by P
            int g3 = g - 6144;
            int j = g3 & 7, lane = (g3 >> 3) & 63, f = g3 >> 9;
            int n = f >> 2, kk = f & 3;
            int hi = lane >> 5, col = n*32 + (lane & 31);
            int k = (j & 3) + 4*hi + 8*(2*(kk & 1) + (j >> 2)) + 32*(kk >> 1);
            wf[g] = (unsigned short)f2bf(W3[k*128 + col]);
        }
    } else {
        // tail copies: 128 blocks x 512 = 65536 = NTOT*3 (pos) + NTOT (batch)
        int i = (b - 28) * 512 + tid;
        if (i < NTOT*3) out[NTOT*128 + i] = pos[i];
        else            out[NTOT*131 + (i - NTOT*3)] = (float)batch[i - NTOT*3];
    }
}

// ============ kernel 2: FUSED search + MLP, 1024 thr = 16 waves = 16 queries/block ============
// LDS: pos SoA (24K) + weights (26K) + snbr (2K) = 53.2 KB -> 2 blocks/CU = 32 waves/CU (HW max).
// Single staging barrier; afterwards each wave runs search -> MLP independently.
__global__ __launch_bounds__(1024, 8) void fused_kernel(
    const float* __restrict__ x, const float* __restrict__ pos,
    const unsigned short* __restrict__ wf, const float* __restrict__ b3,
    float* __restrict__ out)
{
    __shared__ float2 sPxy[NPC];    // 16384 B
    __shared__ float  sPz[NPC];     //  8192 B
    __shared__ int4   sW[1664];     // 26624 B: wg2a(640 int4) | wg3b(1024 int4)
    __shared__ int    snbr[16*32];  //  2048 B: wave-private neighbor slots

    const int tid  = threadIdx.x;
    const int lane = tid & 63, wave = tid >> 6;
    const int e = lane & 31, hi = lane >> 5;
    const int q     = blockIdx.x * 16 + wave;     // this wave's query (global row)
    const int base  = (q >> 11) << 11;            // cloud start row
    const int ql    = q - base;                   // local query index

    // ---- Phase A: parallel staging — half block: pos SoA; other half: weight frags ----
    if (tid < 512) {
        const float4* src = (const float4*)(pos + 3*base);   // 1536 float4
        float4 f0 = src[3*tid], f1 = src[3*tid+1], f2 = src[3*tid+2];
        sPxy[4*tid+0] = make_float2(f0.x, f0.y); sPz[4*tid+0] = f0.z;
        sPxy[4*tid+1] = make_float2(f0.w, f1.x); sPz[4*tid+1] = f1.y;
        sPxy[4*tid+2] = make_float2(f1.z, f1.w); sPz[4*tid+2] = f2.x;
        sPxy[4*tid+3] = make_float2(f2.y, f2.z); sPz[4*tid+3] = f2.w;
    } else {
        const int4* wsrc = (const int4*)(wf + 1024);
        int t = tid - 512;
        #pragma unroll
        for (int it = 0; it < 4; ++it) {
            int idx = it*512 + t;
            if (idx < 1664) sW[idx] = wsrc[idx];
        }
    }
    // layer1 W frags straight to registers (global, L2-resident)
    bf16x8 wA1_0 = *(const bf16x8*)(wf + (0*64 + lane)*8);
    bf16x8 wA1_1 = *(const bf16x8*)(wf + (1*64 + lane)*8);
    float b3v[4];
    #pragma unroll
    for (int n = 0; n < 4; ++n) b3v[n] = b3[n*32 + e];
    __syncthreads();   // the ONLY block-wide barrier

    // ---- Phase B: radius search (exact arith, validated r1-r12); wave-independent ----
    const float2 qxy = sPxy[ql];
    const float qx = qxy.x, qy = qxy.y, qz = sPz[ql];
    int cnt = 0;
    for (int j0 = 0; j0 < NPC && cnt < KMAX; j0 += 256) {
        unsigned long long ms[4];
        bool vs[4];
        #pragma unroll
        for (int s = 0; s < 4; ++s) {
            int j = j0 + s*64 + lane;
            float2 pxy = sPxy[j];
            float  pz  = sPz[j];
            float dx = __fsub_rn(pxy.x, qx);
            float dy = __fsub_rn(pxy.y, qy);
            float dz = __fsub_rn(pz,    qz);
            float d2 = __fadd_rn(__fadd_rn(__fmul_rn(dx,dx), __fmul_rn(dy,dy)),
                                 __fmul_rn(dz,dz));
            vs[s] = d2 <= R2;
            ms[s] = __ballot(vs[s]);
        }
        #pragma unroll
        for (int s = 0; s < 4; ++s) {
            int slot = cnt + mbcnt64(ms[s]);            // v_mbcnt pair, 2 VALU
            if (vs[s] && slot < KMAX) snbr[(wave << 5) + slot] = j0 + s*64 + lane;
            cnt += (int)__popcll(ms[s]);                // wave-uniform -> s_bcnt1
        }
    }
    if (cnt > KMAX) cnt = KMAX;     // wave-uniform

    // ---- Phase C: MLP (r8-validated body); snbr is wave-private, lgkmcnt orders it ----
    int jl = (e < cnt) ? snbr[(wave << 5) + e] : ql;
    float2 pjxy = sPxy[jl];
    float  pjz  = sPz[jl];
    float xj0 = x[3*(base + jl)], xj1 = x[3*(base + jl) + 1], xj2 = x[3*(base + jl) + 2];

    const unsigned int one_w = pkbf(1.0f, 0.0f);
    int4 ow = {0,0,0,0};
    if (!hi) ow.x = (int)one_w;
    const bf16x8 onef = __builtin_bit_cast(bf16x8, ow);   // GEMM2 bias-row B-frag

    float r0 = pjxy.x - qx, r1 = pjxy.y - qy, r2 = pjz - qz;
    int4 mw;
    mw.x = hi ? 0 : (int)pkbf(xj0, xj1);
    mw.y = hi ? 0 : (int)pkbf(xj2, r0);
    mw.z = hi ? 0 : (int)pkbf(r1, r2);
    mw.w = hi ? 0 : (int)one_w;
    bf16x8 msgf = __builtin_bit_cast(bf16x8, mw);

    // layer1 (swapped): C1^T[64 ch][32 e], K=16
    __builtin_amdgcn_s_setprio(1);
    f32x16 acc0 = {}, acc1 = {};
    acc0 = __builtin_amdgcn_mfma_f32_32x32x16_bf16(wA1_0, msgf, acc0, 0, 0, 0);
    acc1 = __builtin_amdgcn_mfma_f32_32x32x16_bf16(wA1_1, msgf, acc1, 0, 0, 0);
    __builtin_amdgcn_s_setprio(0);
    bf16x8 h1f[4];
    h1f[0] = mk_frag(acc0, 0);
    h1f[1] = mk_frag(acc0, 8);
    h1f[2] = mk_frag(acc1, 0);
    h1f[3] = mk_frag(acc1, 8);

    // GEMM2 (swapped): C2^T[64][32], K=80 (bias row via onef)
    __builtin_amdgcn_s_setprio(1);
    f32x16 c20 = {}, c21 = {};
    #pragma unroll
    for (int kk = 0; kk < 4; ++kk) {
        c20 = __builtin_amdgcn_mfma_f32_32x32x16_bf16(
                *(const bf16x8*)&sW[(0*5 + kk)*64 + lane], h1f[kk], c20, 0, 0, 0);
        c21 = __builtin_amdgcn_mfma_f32_32x32x16_bf16(
                *(const bf16x8*)&sW[(1*5 + kk)*64 + lane], h1f[kk], c21, 0, 0, 0);
    }
    c20 = __builtin_amdgcn_mfma_f32_32x32x16_bf16(
            *(const bf16x8*)&sW[(0*5 + 4)*64 + lane], onef, c20, 0, 0, 0);
    c21 = __builtin_amdgcn_mfma_f32_32x32x16_bf16(
            *(const bf16x8*)&sW[(1*5 + 4)*64 + lane], onef, c21, 0, 0, 0);
    __builtin_amdgcn_s_setprio(0);
    bf16x8 h2f[4];
    h2f[0] = mk_frag(c20, 0);
    h2f[1] = mk_frag(c20, 8);
    h2f[2] = mk_frag(c21, 0);
    h2f[3] = mk_frag(c21, 8);

    // GEMM3 (non-swapped): C[32 e][128 out] + fused max over edges
    const bool full = (cnt == 32);
    #pragma unroll
    for (int n = 0; n < 4; ++n) {
        __builtin_amdgcn_s_setprio(1);
        f32x16 c = {};
        #pragma unroll
        for (int kk = 0; kk < 4; ++kk)
            c = __builtin_amdgcn_mfma_f32_32x32x16_bf16(
                    h2f[kk], *(const bf16x8*)&sW[640 + (n*4 + kk)*64 + lane], c, 0, 0, 0);
        __builtin_amdgcn_s_setprio(0);
        float m;
        if (full) {
            // 3-ary nesting -> v_max3_f32 (T17)
            float t0 = fmaxf(fmaxf(c[0],  c[1]),  c[2]);
            float t1 = fmaxf(fmaxf(c[3],  c[4]),  c[5]);
            float t2 = fmaxf(fmaxf(c[6],  c[7]),  c[8]);
            float t3 = fmaxf(fmaxf(c[9],  c[10]), c[11]);
            float t4 = fmaxf(fmaxf(c[12], c[13]), c[14]);
            m = fmaxf(fmaxf(t0, t1), c[15]);
            m = fmaxf(fmaxf(m, t2), t3);
            m = fmaxf(m, t4);
        } else {
            m = -INFINITY;
            #pragma unroll
            for (int reg = 0; reg < 16; ++reg) {
                int r = (reg & 3) + 8*(reg >> 2) + 4*hi;   // edge slot
                m = fmaxf(m, (r < cnt) ? c[reg] : -INFINITY);
            }
        }
        m = fmaxf(m, __shfl_xor(m, 32));
        m += b3v[n];
        if (hi == 0) out[q*128 + n*32 + e] = m;
    }
}

extern "C" void kernel_launch(void* const* d_in, const int* in_sizes, int n_in,
                              void* d_out, int out_size, void* d_ws, size_t ws_size,
                              hipStream_t stream) {
    const float* x     = (const float*)d_in[0];
    const float* pos   = (const float*)d_in[1];
    const int*   batch = (const int*)d_in[2];
    const float* W1    = (const float*)d_in[3];
    const float* b1    = (const float*)d_in[4];
    const float* W2    = (const float*)d_in[5];
    const float* b2    = (const float*)d_in[6];
    const float* W3    = (const float*)d_in[7];
    const float* b3    = (const float*)d_in[8];
    float* out = (float*)d_out;

    unsigned short* wfrag = (unsigned short*)d_ws;   // 14336 bf16 (28 KB)

    prep_small<<<156, 512, 0, stream>>>(pos, batch, W1, b1, W2, b2, W3, wfrag, out);
    fused_kernel<<<1024, 1024, 0, stream>>>(x, pos, wfrag, b3, out);
}